// Round 1
// baseline (15555.450 us; speedup 1.0000x reference)
//
#include <hip/hip_runtime.h>

typedef unsigned short u16;
typedef unsigned int u32;
typedef float f32x16 __attribute__((ext_vector_type(16)));
typedef float f32x4v __attribute__((ext_vector_type(4)));
typedef unsigned int u32x4 __attribute__((ext_vector_type(4)));

#define TT 512
#define NBLK 64

// ---- ws layout (bytes) ----
static const size_t OFF_EMBX = 0;          // u16 [512][64][192]  = 12,582,912
static const size_t OFF_HS   = 12582912;   // u16 [512][64][1024] = 67,108,864
static const size_t OFF_HBUF = 79691776;   // u16 [2][2][512][64] = 262,144
static const size_t OFF_BAR  = 79953920;   // int (zeroed each launch)
static const size_t OFF_FEAT = 79954176;   // f32 [512*64][10]    = 1,310,720
static const size_t OFF_RES  = 81264896;   // f32 [64]
static const size_t WS_NEED  = 81265152;

__device__ inline u32 packbf(float a, float b) {
  u32 ua = __float_as_uint(a); ua += 0x7fffu + ((ua >> 16) & 1u);
  u32 ub = __float_as_uint(b); ub += 0x7fffu + ((ub >> 16) & 1u);
  return (ua >> 16) | (ub & 0xffff0000u);
}
__device__ inline u16 f2b(float a) {
  u32 u = __float_as_uint(a); u += 0x7fffu + ((u >> 16) & 1u);
  return (u16)(u >> 16);
}
__device__ inline float sigm(float x) { return 1.f / (1.f + __expf(-x)); }
__device__ inline float tanhx(float x) {
  float e = __expf(-2.f * fabsf(x));
  float t = (1.f - e) / (1.f + e);
  return (x < 0.f) ? -t : t;
}

// ---- 1. embedding gather: embX[t][b][0..191] bf16 ----
__global__ __launch_bounds__(256) void k_embed(const int* __restrict__ bdata,
                                               const int* __restrict__ brad,
                                               const float* __restrict__ cemb,
                                               const float* __restrict__ remb,
                                               u16* __restrict__ embX) {
  int t = blockIdx.x;
  int tid = threadIdx.x;
#pragma unroll
  for (int r = 0; r < 6; ++r) {
    int cc = r * 256 + tid;           // 0..1535 = 64 b * 24 chunks
    int b = cc / 24;
    int j = cc - b * 24;              // chunk of 8 floats
    int ic = bdata[b * TT + t];
    int ir = brad[b * TT + t];
    const float* src = (j < 16) ? (cemb + (size_t)ic * 128 + j * 8)
                                : (remb + (size_t)ir * 64 + (j - 16) * 8);
    f32x4v f0 = *(const f32x4v*)src;
    f32x4v f1 = *(const f32x4v*)(src + 4);
    u32x4 o;
    o[0] = packbf(f0[0], f0[1]); o[1] = packbf(f0[2], f0[3]);
    o[2] = packbf(f1[0], f1[1]); o[3] = packbf(f1[2], f1[3]);
    *(u32x4*)(embX + ((size_t)t * 64 + b) * 192 + j * 8) = o;
  }
}

// ---- 2. persistent bidirectional LSTM ----
// 64 blocks: blk>>5 = dir, (blk&31)*16 = hidden slice j0. 256 thr = 4 waves (m,n).
// Per step: gates[64 rows(i,f,g,o x16)][64 b] = Wcat(regs,bf16) @ [h;x](LDS/global,bf16)
__global__ __launch_bounds__(256, 1) void k_lstm(
    const u16* __restrict__ embX, u16* __restrict__ hbuf, u16* __restrict__ hs,
    const float* __restrict__ wihf, const float* __restrict__ whhf, const float* __restrict__ bf,
    const float* __restrict__ wihb, const float* __restrict__ whhb, const float* __restrict__ bb,
    int* __restrict__ bar) {
  __shared__ char smem[65536];
  u16* smh = (u16*)smem;                 // stage phase: h as [b][512] swizzled
  float* gl = (float*)smem;              // gates phase: [64][68] f32 (aliased)
  u16* hl = (u16*)(smem + 17408);        // h-out tile [b][16]

  const int tid = threadIdx.x;
  const int lane = tid & 63;
  const int wid = tid >> 6;
  const int blk = blockIdx.x;
  const int dir = blk >> 5;
  const int j0 = (blk & 31) << 4;

  const float* wih = dir ? wihb : wihf;
  const float* whh = dir ? whhb : whhf;
  const float* bias = dir ? bb : bf;

  const int m = wid >> 1, n = wid & 1;
  const int l31 = lane & 31;
  const int hi = lane >> 5;

  // A-operand (weights) -> registers, once. local row lr = strip*16 + r
  const int lr = m * 32 + l31;
  const int strip = lr >> 4, rr = lr & 15;
  const int grow = strip * 512 + j0 + rr;
  const float* pih = wih + (size_t)grow * 192 + 8 * hi;
  const float* phh = whh + (size_t)grow * 512 + 8 * hi;
  u32x4 aw[44];
#pragma unroll
  for (int kt = 0; kt < 44; ++kt) {
    const float* p = (kt < 12) ? (pih + kt * 16) : (phh + (kt - 12) * 16);
    f32x4v f0 = *(const f32x4v*)p;
    f32x4v f1 = *(const f32x4v*)(p + 4);
    u32x4 a;
    a[0] = packbf(f0[0], f0[1]); a[1] = packbf(f0[2], f0[3]);
    a[2] = packbf(f1[0], f1[1]); a[3] = packbf(f1[2], f1[3]);
    aw[kt] = a;
  }

  u16* hb_d = hbuf + dir * 65536;        // [2 parity][512 k][64 b]

  const int bb_ = n * 32 + l31;          // batch column for B-frags
  const int swz = (bb_ & 15) << 4;       // byte swizzle within 1KB row
  char* hbase = smem + bb_ * 1024;
  const int hoff = hi * 16;

  float creg[4] = {0.f, 0.f, 0.f, 0.f};  // cell state, fixed (j,b) per thread
  const int pb = tid & 63;
  const int pw = tid >> 6;

  for (int t = 0; t < TT; ++t) {
    const int par = t & 1;
    const int tx = dir ? (511 - t) : t;

    // ---- stage h: global [k][b] -> LDS [b][k] (XOR-swizzled), coalesced reads
    {
      const u16* src = hb_d + par * 32768;
      for (int r = 0; r < 16; ++r) {
        int c = r * 256 + tid;
        int sb = c & 63;
        int k0 = (c >> 6) * 8;
        u16 e0 = src[(k0 + 0) * 64 + sb];
        u16 e1 = src[(k0 + 1) * 64 + sb];
        u16 e2 = src[(k0 + 2) * 64 + sb];
        u16 e3 = src[(k0 + 3) * 64 + sb];
        u16 e4 = src[(k0 + 4) * 64 + sb];
        u16 e5 = src[(k0 + 5) * 64 + sb];
        u16 e6 = src[(k0 + 6) * 64 + sb];
        u16 e7 = src[(k0 + 7) * 64 + sb];
        int kk = k0 ^ ((sb & 15) << 3);
        u32x4 v;
        v[0] = (u32)e0 | ((u32)e1 << 16);
        v[1] = (u32)e2 | ((u32)e3 << 16);
        v[2] = (u32)e4 | ((u32)e5 << 16);
        v[3] = (u32)e6 | ((u32)e7 << 16);
        *(u32x4*)(smh + sb * 512 + kk) = v;
      }
    }
    __syncthreads();

    // ---- MFMA: acc[64g][64b] tile (m,n), K = 512(h) + 192(x)
    f32x16 acc;
#pragma unroll
    for (int i = 0; i < 16; ++i) acc[i] = 0.f;
    asm volatile("s_nop 7\ns_nop 7");
    const u16* xbase = embX + ((size_t)tx * 64 + bb_) * 192 + 8 * hi;
#pragma unroll
    for (int kt = 0; kt < 44; ++kt) {
      u32x4 bfrag;
      if (kt < 32) {
        bfrag = *(const u32x4*)(hbase + ((kt * 32 + hoff) ^ swz));
      } else {
        bfrag = *(const u32x4*)(xbase + (kt - 32) * 16);
      }
      asm("v_mfma_f32_32x32x16_bf16 %0, %1, %2, %0" : "+v"(acc) : "v"(aw[kt]), "v"(bfrag));
    }
    asm volatile("s_nop 7\ns_nop 7\ns_nop 7");
    __syncthreads();  // everyone done reading smh before gl alias write

    // ---- gates -> LDS  (D layout: col=lane&31, row=(r&3)+8*(r>>2)+4*(lane>>5))
#pragma unroll
    for (int r = 0; r < 16; ++r) {
      int row = (r & 3) + 8 * (r >> 2) + 4 * hi;
      gl[(m * 32 + row) * 68 + (n * 32 + l31)] = acc[r];
    }
    __syncthreads();

    // ---- pointwise LSTM cell (fp32)
    {
      u16* dsth = hb_d + (par ^ 1) * 32768;
#pragma unroll
      for (int q = 0; q < 4; ++q) {
        int j = pw + q * 4;
        float gi = gl[j * 68 + pb] + bias[j0 + j];
        float gf = gl[(16 + j) * 68 + pb] + bias[512 + j0 + j];
        float gg = gl[(32 + j) * 68 + pb] + bias[1024 + j0 + j];
        float go = gl[(48 + j) * 68 + pb] + bias[1536 + j0 + j];
        float cn = sigm(gf) * creg[q] + sigm(gi) * tanhx(gg);
        creg[q] = cn;
        float h = sigm(go) * tanhx(cn);
        u16 h16 = f2b(h);
        dsth[(j0 + j) * 64 + pb] = h16;   // coalesced 128B rows
        hl[pb * 16 + j] = h16;
      }
    }
    __syncthreads();

    // ---- hs output [t][b][1024] (coalesced 16B chunks)
    if (tid < 128) {
      int ob = tid >> 1, hf = tid & 1;
      u32x4 v = *(const u32x4*)(hl + ob * 16 + hf * 8);
      *(u32x4*)(hs + ((size_t)tx * 64 + ob) * 1024 + dir * 512 + j0 + hf * 8) = v;
    }

    // ---- device barrier (all 64 blocks co-resident)
    __threadfence();
    __syncthreads();
    if (tid == 0) {
      __hip_atomic_fetch_add(bar, 1, __ATOMIC_RELAXED, __HIP_MEMORY_SCOPE_AGENT);
      int tgt = (t + 1) * NBLK;
      int guard = 0;
      while (__hip_atomic_load(bar, __ATOMIC_RELAXED, __HIP_MEMORY_SCOPE_AGENT) < tgt) {
        __builtin_amdgcn_s_sleep(1);
        if (++guard > 4000000) break;  // failsafe: wrong answer > hang
      }
    }
    __syncthreads();
    __threadfence();
  }
}

// ---- 3. emission: feats[row=t*64+b][c] = hs_row . w_cls[c] + b_cls[c] ----
__global__ __launch_bounds__(256) void k_emis(const u16* __restrict__ hs,
                                              const float* __restrict__ wcls,
                                              const float* __restrict__ bcls,
                                              float* __restrict__ feats) {
  __shared__ float wl[10240];
  int tid = threadIdx.x;
  for (int i = tid; i < 10240; i += 256) wl[i] = wcls[i];
  __syncthreads();
  int row = blockIdx.x * 256 + tid;
  const u16* hrow = hs + (size_t)row * 1024;
  float acc[10];
#pragma unroll
  for (int c = 0; c < 10; ++c) acc[c] = bcls[c];
  for (int k0 = 0; k0 < 1024; k0 += 8) {
    u32x4 v = *(const u32x4*)(hrow + k0);
    float x0 = __uint_as_float(v[0] << 16);
    float x1 = __uint_as_float(v[0] & 0xffff0000u);
    float x2 = __uint_as_float(v[1] << 16);
    float x3 = __uint_as_float(v[1] & 0xffff0000u);
    float x4 = __uint_as_float(v[2] << 16);
    float x5 = __uint_as_float(v[2] & 0xffff0000u);
    float x6 = __uint_as_float(v[3] << 16);
    float x7 = __uint_as_float(v[3] & 0xffff0000u);
#pragma unroll
    for (int c = 0; c < 10; ++c) {
      const float* w = &wl[c * 1024 + k0];
      f32x4v wa = *(const f32x4v*)w;
      f32x4v wb = *(const f32x4v*)(w + 4);
      acc[c] += x0 * wa[0] + x1 * wa[1] + x2 * wa[2] + x3 * wa[3] +
                x4 * wb[0] + x5 * wb[1] + x6 * wb[2] + x7 * wb[3];
    }
  }
#pragma unroll
  for (int c = 0; c < 10; ++c) feats[(size_t)row * 10 + c] = acc[c];
}

// ---- 4. CRF forward + gold score, one wave per batch element ----
__global__ void k_crf(const float* __restrict__ feats, const float* __restrict__ trans,
                      const int* __restrict__ btag, float* __restrict__ res) {
  int b = blockIdx.x;
  int lane = threadIdx.x;
  float tr[10];
  int to = lane < 10 ? lane : 9;
#pragma unroll
  for (int f = 0; f < 10; ++f) tr[f] = trans[to * 10 + f];
  float al[10];
#pragma unroll
  for (int f = 0; f < 10; ++f) al[f] = (f == 8) ? 0.f : -10000.f;  // START_ID=8
  for (int t = 0; t < 512; ++t) {
    float fe = (lane < 10) ? feats[((size_t)t * 64 + b) * 10 + lane] : 0.f;
    float mx = -3.0e38f;
#pragma unroll
    for (int f = 0; f < 10; ++f) mx = fmaxf(mx, al[f] + tr[f]);
    float s = 0.f;
#pragma unroll
    for (int f = 0; f < 10; ++f) s += __expf(al[f] + tr[f] - mx);
    float an = mx + __logf(s) + fe;
#pragma unroll
    for (int f = 0; f < 10; ++f) al[f] = __shfl(an, f);
  }
  float mx = -3.0e38f;
#pragma unroll
  for (int f = 0; f < 10; ++f) mx = fmaxf(mx, al[f]);
  float s = 0.f;
#pragma unroll
  for (int f = 0; f < 10; ++f) s += __expf(al[f] - mx);
  float fwd = mx + __logf(s);
  // gold score
  float g = 0.f;
  for (int t = lane; t < 512; t += 64) {
    int tg = btag[b * 512 + t];
    int pv = (t == 0) ? 8 : btag[b * 512 + t - 1];
    g += trans[tg * 10 + pv] + feats[((size_t)t * 64 + b) * 10 + tg];
  }
#pragma unroll
  for (int off = 32; off > 0; off >>= 1) g += __shfl_down(g, off);
  if (lane == 0) res[b] = fwd - g;
}

// ---- 5. final reduce ----
__global__ void k_fin(const float* __restrict__ res, float* __restrict__ out) {
  float v = res[threadIdx.x];
#pragma unroll
  for (int off = 32; off > 0; off >>= 1) v += __shfl_down(v, off);
  if (threadIdx.x == 0) out[0] = v * (1.f / 64.f);
}

extern "C" void kernel_launch(void* const* d_in, const int* in_sizes, int n_in,
                              void* d_out, int out_size, void* d_ws, size_t ws_size,
                              hipStream_t stream) {
  (void)in_sizes; (void)n_in; (void)out_size;
  if (ws_size < WS_NEED) return;  // visible failure instead of OOB

  const int* bdata = (const int*)d_in[0];
  const int* brad  = (const int*)d_in[1];
  const int* btag  = (const int*)d_in[2];
  const float* cemb = (const float*)d_in[3];
  const float* remb = (const float*)d_in[4];
  const float* wihf = (const float*)d_in[5];
  const float* whhf = (const float*)d_in[6];
  const float* bf   = (const float*)d_in[7];
  const float* wihb = (const float*)d_in[8];
  const float* whhb = (const float*)d_in[9];
  const float* bb   = (const float*)d_in[10];
  const float* wcls = (const float*)d_in[11];
  const float* bcls = (const float*)d_in[12];
  const float* trans = (const float*)d_in[13];

  char* ws = (char*)d_ws;
  u16* embX = (u16*)(ws + OFF_EMBX);
  u16* hs   = (u16*)(ws + OFF_HS);
  u16* hbuf = (u16*)(ws + OFF_HBUF);
  int* bar  = (int*)(ws + OFF_BAR);
  float* feats = (float*)(ws + OFF_FEAT);
  float* res = (float*)(ws + OFF_RES);

  // zero h0 (both dirs, both parities) + barrier counter, every launch
  hipMemsetAsync(ws + OFF_HBUF, 0, 262144 + 256, stream);

  k_embed<<<512, 256, 0, stream>>>(bdata, brad, cemb, remb, embX);
  k_lstm<<<64, 256, 0, stream>>>(embX, hbuf, hs, wihf, whhf, bf, wihb, whhb, bb, bar);
  k_emis<<<128, 256, 0, stream>>>(hs, wcls, bcls, feats);
  k_crf<<<64, 64, 0, stream>>>(feats, trans, btag, res);
  k_fin<<<1, 64, 0, stream>>>(res, (float*)d_out);
}

// Round 3
// 3587.389 us; speedup vs baseline: 4.3361x; 4.3361x over previous
//
#include <hip/hip_runtime.h>

typedef unsigned short u16;
typedef unsigned int u32;
typedef float f32x16 __attribute__((ext_vector_type(16)));
typedef float f32x4v __attribute__((ext_vector_type(4)));
typedef unsigned int u32x4 __attribute__((ext_vector_type(4)));
typedef unsigned int u32x2 __attribute__((ext_vector_type(2)));

#define TT 512
#define NBLK 64

// ---- ws layout (bytes) ----
static const size_t OFF_EMBX = 0;          // u16 [512][64][192]  = 12,582,912
static const size_t OFF_HS   = 12582912;   // u16 [512][64][1024] = 67,108,864
static const size_t OFF_HBUF = 79691776;   // u16 [dir][par][64 b][512 k] = 262,144
static const size_t OFF_BAR  = 79953920;   // 256 B of counters (zeroed each launch)
static const size_t OFF_FEAT = 79954176;   // f32 [512*64][10]    = 1,310,720
static const size_t OFF_RES  = 81264896;   // f32 [64]
static const size_t WS_NEED  = 81265152;

__device__ inline u32 packbf(float a, float b) {
  u32 ua = __float_as_uint(a); ua += 0x7fffu + ((ua >> 16) & 1u);
  u32 ub = __float_as_uint(b); ub += 0x7fffu + ((ub >> 16) & 1u);
  return (ua >> 16) | (ub & 0xffff0000u);
}
__device__ inline u16 f2b(float a) {
  u32 u = __float_as_uint(a); u += 0x7fffu + ((u >> 16) & 1u);
  return (u16)(u >> 16);
}
__device__ inline float sigm(float x) { return 1.f / (1.f + __expf(-x)); }
__device__ inline float tanhx(float x) {
  float e = __expf(-2.f * fabsf(x));
  float t = (1.f - e) / (1.f + e);
  return (x < 0.f) ? -t : t;
}

// L3-coherent (L1/L2-bypassing) access helpers — cross-XCD exchange w/o fences
__device__ inline u32x4 ldg_cc(const u16* p) {
  u32x4 r;
  asm volatile("global_load_dwordx4 %0, %1, off sc0 sc1"
               : "=v"(r) : "v"(p) : "memory");
  return r;
}
__device__ inline void stg_cc8(u16* p, u32x2 v) {
  asm volatile("global_store_dwordx2 %0, %1, off sc0 sc1"
               :: "v"(p), "v"(v) : "memory");
}

// ---- 1. embedding gather: embX[t][b][0..191] bf16 ----
__global__ __launch_bounds__(256) void k_embed(const int* __restrict__ bdata,
                                               const int* __restrict__ brad,
                                               const float* __restrict__ cemb,
                                               const float* __restrict__ remb,
                                               u16* __restrict__ embX) {
  int t = blockIdx.x;
  int tid = threadIdx.x;
#pragma unroll
  for (int r = 0; r < 6; ++r) {
    int cc = r * 256 + tid;           // 0..1535 = 64 b * 24 chunks
    int b = cc / 24;
    int j = cc - b * 24;              // chunk of 8 floats
    int ic = bdata[b * TT + t];
    int ir = brad[b * TT + t];
    const float* src = (j < 16) ? (cemb + (size_t)ic * 128 + j * 8)
                                : (remb + (size_t)ir * 64 + (j - 16) * 8);
    f32x4v f0 = *(const f32x4v*)src;
    f32x4v f1 = *(const f32x4v*)(src + 4);
    u32x4 o;
    o[0] = packbf(f0[0], f0[1]); o[1] = packbf(f0[2], f0[3]);
    o[2] = packbf(f1[0], f1[1]); o[3] = packbf(f1[2], f1[3]);
    *(u32x4*)(embX + ((size_t)t * 64 + b) * 192 + j * 8) = o;
  }
}

// ---- 2. persistent bidirectional LSTM ----
// 64 blocks: blk>>5 = dir, (blk&31)*16 = hidden slice j0. 256 thr = 4 waves.
// h exchanged transposed [b][k] through L3 (sc0 sc1); per-direction barrier.
__global__ __launch_bounds__(256, 1) void k_lstm(
    const u16* __restrict__ embX, u16* __restrict__ hbuf, u16* __restrict__ hs,
    const float* __restrict__ wihf, const float* __restrict__ whhf, const float* __restrict__ bf,
    const float* __restrict__ wihb, const float* __restrict__ whhb, const float* __restrict__ bb,
    int* __restrict__ bar) {
  __shared__ char smem[65536];
  u16* smh = (u16*)smem;                 // stage phase: h as [b][512] swizzled
  float* gl = (float*)smem;              // gates phase: [64][68] f32 (aliased)
  u16* hl = (u16*)(smem + 17408);        // h-out tile [b][16]

  const int tid = threadIdx.x;
  const int lane = tid & 63;
  const int wid = tid >> 6;
  const int blk = blockIdx.x;
  const int dir = blk >> 5;
  const int j0 = (blk & 31) << 4;

  const float* wih = dir ? wihb : wihf;
  const float* whh = dir ? whhb : whhf;
  const float* bias = dir ? bb : bf;

  const int m = wid >> 1, n = wid & 1;
  const int l31 = lane & 31;
  const int hi = lane >> 5;

  // A-operand (weights) -> registers, once. local row lr = strip*16 + r
  const int lr = m * 32 + l31;
  const int strip = lr >> 4, rr = lr & 15;
  const int grow = strip * 512 + j0 + rr;
  const float* pih = wih + (size_t)grow * 192 + 8 * hi;
  const float* phh = whh + (size_t)grow * 512 + 8 * hi;
  u32x4 aw[44];
#pragma unroll
  for (int kt = 0; kt < 44; ++kt) {
    const float* p = (kt < 12) ? (pih + kt * 16) : (phh + (kt - 12) * 16);
    f32x4v f0 = *(const f32x4v*)p;
    f32x4v f1 = *(const f32x4v*)(p + 4);
    u32x4 a;
    a[0] = packbf(f0[0], f0[1]); a[1] = packbf(f0[2], f0[3]);
    a[2] = packbf(f1[0], f1[1]); a[3] = packbf(f1[2], f1[3]);
    aw[kt] = a;
  }

  u16* hb_dT = hbuf + dir * 65536;       // [2 parity][64 b][512 k]

  const int bb_ = n * 32 + l31;          // batch column for B-frags
  const int swzr = (bb_ & 15) << 4;      // byte swizzle within 1KB row
  const char* hbase = smem + bb_ * 1024;
  const int hoff = hi * 16;

  // pointwise mapping: thread -> (batch pb, 4 consecutive j at pj)
  const int pb = tid >> 2;
  const int pj = (tid & 3) * 4;
  float creg[4] = {0.f, 0.f, 0.f, 0.f};
  float bI[4], bF[4], bG[4], bO[4];
#pragma unroll
  for (int q = 0; q < 4; ++q) {
    bI[q] = bias[j0 + pj + q];
    bF[q] = bias[512 + j0 + pj + q];
    bG[q] = bias[1024 + j0 + pj + q];
    bO[q] = bias[1536 + j0 + pj + q];
  }

  int* mybar = bar + dir * 32;           // 128B apart, BOTH inside zeroed 256B

  for (int t = 0; t < TT; ++t) {
    const int par = t & 1;
    const int tx = dir ? (511 - t) : t;

    // ---- stage h_T: global [b][k] (L3) -> LDS [b][k^swz], coalesced dwordx4
    {
      const u16* src = hb_dT + par * 32768;
#pragma unroll
      for (int half = 0; half < 2; ++half) {
        u32x4 v[8];
#pragma unroll
        for (int r = 0; r < 8; ++r) {
          int b = (half * 8 + r) * 4 + wid;
          v[r] = ldg_cc(src + b * 512 + lane * 8);
        }
        asm volatile("s_waitcnt vmcnt(0)" ::: "memory");
#pragma unroll
        for (int r = 0; r < 8; ++r) {
          int b = (half * 8 + r) * 4 + wid;
          int kk = (lane * 8) ^ ((b & 15) << 3);
          *(u32x4*)(smh + b * 512 + kk) = v[r];
        }
      }
    }
    __syncthreads();

    // ---- MFMA: acc[64g][64b] tile (m,n), K = 512(h) + 192(x)
    f32x16 acc;
#pragma unroll
    for (int i = 0; i < 16; ++i) acc[i] = 0.f;
    asm volatile("s_nop 7\ns_nop 7");
    const u16* xbase = embX + ((size_t)tx * 64 + bb_) * 192 + 8 * hi;
#pragma unroll
    for (int kt = 0; kt < 44; ++kt) {
      u32x4 bfrag;
      if (kt < 32) {
        bfrag = *(const u32x4*)(hbase + ((kt * 32 + hoff) ^ swzr));
      } else {
        bfrag = *(const u32x4*)(xbase + (kt - 32) * 16);
      }
      asm("v_mfma_f32_32x32x16_bf16 %0, %1, %2, %0" : "+v"(acc) : "v"(aw[kt]), "v"(bfrag));
    }
    asm volatile("s_nop 7\ns_nop 7\ns_nop 7");
    __syncthreads();  // everyone done reading smh before gl alias write

    // ---- gates -> LDS  (D layout: col=lane&31, row=(r&3)+8*(r>>2)+4*(lane>>5))
#pragma unroll
    for (int r = 0; r < 16; ++r) {
      int row = (r & 3) + 8 * (r >> 2) + 4 * hi;
      gl[(m * 32 + row) * 68 + (n * 32 + l31)] = acc[r];
    }
    __syncthreads();

    // ---- pointwise LSTM cell (fp32); h -> global transposed [b][k] via L3
    {
      u16* dstT = hb_dT + (par ^ 1) * 32768;
      u32 hp0 = 0, hp1 = 0;
#pragma unroll
      for (int q = 0; q < 4; ++q) {
        int j = pj + q;
        float gi = gl[j * 68 + pb] + bI[q];
        float gf = gl[(16 + j) * 68 + pb] + bF[q];
        float gg = gl[(32 + j) * 68 + pb] + bG[q];
        float go = gl[(48 + j) * 68 + pb] + bO[q];
        float cn = sigm(gf) * creg[q] + sigm(gi) * tanhx(gg);
        creg[q] = cn;
        float h = sigm(go) * tanhx(cn);
        u32 h16 = (u32)f2b(h);
        if (q == 0) hp0 = h16;
        else if (q == 1) hp0 |= h16 << 16;
        else if (q == 2) hp1 = h16;
        else hp1 |= h16 << 16;
      }
      u32x2 hv; hv[0] = hp0; hv[1] = hp1;
      stg_cc8(dstT + pb * 512 + j0 + pj, hv);
      *(u32x2*)(hl + pb * 16 + pj) = hv;
    }
    __syncthreads();

    // ---- hs output [t][b][1024] (coalesced 16B chunks, plain cached stores)
    if (tid < 128) {
      int ob = tid >> 1, hf = tid & 1;
      u32x4 v = *(const u32x4*)(hl + ob * 16 + hf * 8);
      *(u32x4*)(hs + ((size_t)tx * 64 + ob) * 1024 + dir * 512 + j0 + hf * 8) = v;
    }

    // ---- per-direction barrier (32 blocks), no cache fences needed
    if (t != TT - 1) {
      asm volatile("s_waitcnt vmcnt(0)" ::: "memory");
      __syncthreads();
      if (tid == 0) {
        __hip_atomic_fetch_add(mybar, 1, __ATOMIC_RELAXED, __HIP_MEMORY_SCOPE_AGENT);
        int tgt = (t + 1) * 32;
        int guard = 0;
        while (__hip_atomic_load(mybar, __ATOMIC_RELAXED, __HIP_MEMORY_SCOPE_AGENT) < tgt) {
          __builtin_amdgcn_s_sleep(1);
          if (++guard > 100000) break;  // failsafe: wrong answer > hang
        }
      }
      __syncthreads();
    }
  }
}

// ---- 3. emission: feats[row=t*64+b][c] = hs_row . w_cls[c] + b_cls[c] ----
__global__ __launch_bounds__(256) void k_emis(const u16* __restrict__ hs,
                                              const float* __restrict__ wcls,
                                              const float* __restrict__ bcls,
                                              float* __restrict__ feats) {
  __shared__ float wl[10240];
  int tid = threadIdx.x;
  for (int i = tid; i < 10240; i += 256) wl[i] = wcls[i];
  __syncthreads();
  int row = blockIdx.x * 256 + tid;
  const u16* hrow = hs + (size_t)row * 1024;
  float acc[10];
#pragma unroll
  for (int c = 0; c < 10; ++c) acc[c] = bcls[c];
  for (int k0 = 0; k0 < 1024; k0 += 8) {
    u32x4 v = *(const u32x4*)(hrow + k0);
    float x0 = __uint_as_float(v[0] << 16);
    float x1 = __uint_as_float(v[0] & 0xffff0000u);
    float x2 = __uint_as_float(v[1] << 16);
    float x3 = __uint_as_float(v[1] & 0xffff0000u);
    float x4 = __uint_as_float(v[2] << 16);
    float x5 = __uint_as_float(v[2] & 0xffff0000u);
    float x6 = __uint_as_float(v[3] << 16);
    float x7 = __uint_as_float(v[3] & 0xffff0000u);
#pragma unroll
    for (int c = 0; c < 10; ++c) {
      const float* w = &wl[c * 1024 + k0];
      f32x4v wa = *(const f32x4v*)w;
      f32x4v wb = *(const f32x4v*)(w + 4);
      acc[c] += x0 * wa[0] + x1 * wa[1] + x2 * wa[2] + x3 * wa[3] +
                x4 * wb[0] + x5 * wb[1] + x6 * wb[2] + x7 * wb[3];
    }
  }
#pragma unroll
  for (int c = 0; c < 10; ++c) feats[(size_t)row * 10 + c] = acc[c];
}

// ---- 4. CRF forward + gold score, one wave per batch element ----
__global__ void k_crf(const float* __restrict__ feats, const float* __restrict__ trans,
                      const int* __restrict__ btag, float* __restrict__ res) {
  int b = blockIdx.x;
  int lane = threadIdx.x;
  float tr[10];
  int to = lane < 10 ? lane : 9;
#pragma unroll
  for (int f = 0; f < 10; ++f) tr[f] = trans[to * 10 + f];
  float al[10];
#pragma unroll
  for (int f = 0; f < 10; ++f) al[f] = (f == 8) ? 0.f : -10000.f;  // START_ID=8
  for (int t = 0; t < 512; ++t) {
    float fe = (lane < 10) ? feats[((size_t)t * 64 + b) * 10 + lane] : 0.f;
    float mx = -3.0e38f;
#pragma unroll
    for (int f = 0; f < 10; ++f) mx = fmaxf(mx, al[f] + tr[f]);
    float s = 0.f;
#pragma unroll
    for (int f = 0; f < 10; ++f) s += __expf(al[f] + tr[f] - mx);
    float an = mx + __logf(s) + fe;
#pragma unroll
    for (int f = 0; f < 10; ++f) al[f] = __shfl(an, f);
  }
  float mx = -3.0e38f;
#pragma unroll
  for (int f = 0; f < 10; ++f) mx = fmaxf(mx, al[f]);
  float s = 0.f;
#pragma unroll
  for (int f = 0; f < 10; ++f) s += __expf(al[f] - mx);
  float fwd = mx + __logf(s);
  // gold score
  float g = 0.f;
  for (int t = lane; t < 512; t += 64) {
    int tg = btag[b * 512 + t];
    int pv = (t == 0) ? 8 : btag[b * 512 + t - 1];
    g += trans[tg * 10 + pv] + feats[((size_t)t * 64 + b) * 10 + tg];
  }
#pragma unroll
  for (int off = 32; off > 0; off >>= 1) g += __shfl_down(g, off);
  if (lane == 0) res[b] = fwd - g;
}

// ---- 5. final reduce ----
__global__ void k_fin(const float* __restrict__ res, float* __restrict__ out) {
  float v = res[threadIdx.x];
#pragma unroll
  for (int off = 32; off > 0; off >>= 1) v += __shfl_down(v, off);
  if (threadIdx.x == 0) out[0] = v * (1.f / 64.f);
}

extern "C" void kernel_launch(void* const* d_in, const int* in_sizes, int n_in,
                              void* d_out, int out_size, void* d_ws, size_t ws_size,
                              hipStream_t stream) {
  (void)in_sizes; (void)n_in; (void)out_size;
  if (ws_size < WS_NEED) return;  // visible failure instead of OOB

  const int* bdata = (const int*)d_in[0];
  const int* brad  = (const int*)d_in[1];
  const int* btag  = (const int*)d_in[2];
  const float* cemb = (const float*)d_in[3];
  const float* remb = (const float*)d_in[4];
  const float* wihf = (const float*)d_in[5];
  const float* whhf = (const float*)d_in[6];
  const float* bf   = (const float*)d_in[7];
  const float* wihb = (const float*)d_in[8];
  const float* whhb = (const float*)d_in[9];
  const float* bb   = (const float*)d_in[10];
  const float* wcls = (const float*)d_in[11];
  const float* bcls = (const float*)d_in[12];
  const float* trans = (const float*)d_in[13];

  char* ws = (char*)d_ws;
  u16* embX = (u16*)(ws + OFF_EMBX);
  u16* hs   = (u16*)(ws + OFF_HS);
  u16* hbuf = (u16*)(ws + OFF_HBUF);
  int* bar  = (int*)(ws + OFF_BAR);
  float* feats = (float*)(ws + OFF_FEAT);
  float* res = (float*)(ws + OFF_RES);

  // zero h0 (both dirs, both parities) + barrier counters, every launch
  hipMemsetAsync(ws + OFF_HBUF, 0, 262144 + 256, stream);

  k_embed<<<512, 256, 0, stream>>>(bdata, brad, cemb, remb, embX);
  k_lstm<<<64, 256, 0, stream>>>(embX, hbuf, hs, wihf, whhf, bf, wihb, whhb, bb, bar);
  k_emis<<<128, 256, 0, stream>>>(hs, wcls, bcls, feats);
  k_crf<<<64, 64, 0, stream>>>(feats, trans, btag, res);
  k_fin<<<1, 64, 0, stream>>>(res, (float*)d_out);
}

// Round 4
// 3217.751 us; speedup vs baseline: 4.8343x; 1.1149x over previous
//
#include <hip/hip_runtime.h>

typedef unsigned short u16;
typedef unsigned int u32;
typedef float f32x16 __attribute__((ext_vector_type(16)));
typedef float f32x4v __attribute__((ext_vector_type(4)));
typedef unsigned int u32x4 __attribute__((ext_vector_type(4)));
typedef unsigned int u32x2 __attribute__((ext_vector_type(2)));

#define TT 512
#define NBLK 64

// ---- ws layout (bytes) ----
static const size_t OFF_EMBX = 0;          // u16 [512][64][192]  = 12,582,912
static const size_t OFF_HS   = 12582912;   // u16 [512][64][1024] = 67,108,864
static const size_t OFF_HBUF = 79691776;   // u16 [dir][par][64 b][512 k] = 262,144
static const size_t OFF_BAR  = 79953920;   // int flags[2][64] (512 B, zeroed each launch)
static const size_t OFF_FEAT = 79954176;   // f32 [512*64][10]    = 1,310,720
static const size_t OFF_RES  = 81264896;   // f32 [64]
static const size_t WS_NEED  = 81265152;

__device__ inline u32 packbf(float a, float b) {
  u32 ua = __float_as_uint(a); ua += 0x7fffu + ((ua >> 16) & 1u);
  u32 ub = __float_as_uint(b); ub += 0x7fffu + ((ub >> 16) & 1u);
  return (ua >> 16) | (ub & 0xffff0000u);
}
__device__ inline u16 f2b(float a) {
  u32 u = __float_as_uint(a); u += 0x7fffu + ((u >> 16) & 1u);
  return (u16)(u >> 16);
}
__device__ inline float sigm(float x) { return 1.f / (1.f + __expf(-x)); }
__device__ inline float tanhx(float x) {
  float e = __expf(-2.f * fabsf(x));
  float t = (1.f - e) / (1.f + e);
  return (x < 0.f) ? -t : t;
}

// L3-coherent (L1/L2-bypassing) access helpers — cross-XCD exchange w/o fences
__device__ inline u32x4 ldg_cc(const u16* p) {
  u32x4 r;
  asm volatile("global_load_dwordx4 %0, %1, off sc0 sc1"
               : "=v"(r) : "v"(p) : "memory");
  return r;
}
__device__ inline void stg_cc8(u16* p, u32x2 v) {
  asm volatile("global_store_dwordx2 %0, %1, off sc0 sc1"
               :: "v"(p), "v"(v) : "memory");
}
__device__ inline int ldflag(const int* p) {
  int r;
  asm volatile("global_load_dword %0, %1, off sc0 sc1"
               : "=v"(r) : "v"(p) : "memory");
  asm volatile("s_waitcnt vmcnt(0)" ::: "memory");
  return r;
}
__device__ inline void stflag(int* p, int v) {
  asm volatile("global_store_dword %0, %1, off sc0 sc1"
               :: "v"(p), "v"(v) : "memory");
}

// ---- 1. embedding gather: embX[t][b][0..191] bf16 ----
__global__ __launch_bounds__(256) void k_embed(const int* __restrict__ bdata,
                                               const int* __restrict__ brad,
                                               const float* __restrict__ cemb,
                                               const float* __restrict__ remb,
                                               u16* __restrict__ embX) {
  int t = blockIdx.x;
  int tid = threadIdx.x;
#pragma unroll
  for (int r = 0; r < 6; ++r) {
    int cc = r * 256 + tid;           // 0..1535 = 64 b * 24 chunks
    int b = cc / 24;
    int j = cc - b * 24;              // chunk of 8 floats
    int ic = bdata[b * TT + t];
    int ir = brad[b * TT + t];
    const float* src = (j < 16) ? (cemb + (size_t)ic * 128 + j * 8)
                                : (remb + (size_t)ir * 64 + (j - 16) * 8);
    f32x4v f0 = *(const f32x4v*)src;
    f32x4v f1 = *(const f32x4v*)(src + 4);
    u32x4 o;
    o[0] = packbf(f0[0], f0[1]); o[1] = packbf(f0[2], f0[3]);
    o[2] = packbf(f1[0], f1[1]); o[3] = packbf(f1[2], f1[3]);
    *(u32x4*)(embX + ((size_t)t * 64 + b) * 192 + j * 8) = o;
  }
}

// ---- 2. persistent bidirectional LSTM ----
// 64 blocks: blk>>5 = dir, (blk&31)*16 = hidden slice j0. 256 thr = 4 waves.
// h exchanged transposed [b][k] through L3 (sc0 sc1).
// Sync: per-producer ready-flags, consumer gathers all 32 in ONE vector load.
__global__ __launch_bounds__(256, 1) void k_lstm(
    const u16* __restrict__ embX, u16* __restrict__ hbuf, u16* __restrict__ hs,
    const float* __restrict__ wihf, const float* __restrict__ whhf, const float* __restrict__ bf,
    const float* __restrict__ wihb, const float* __restrict__ whhb, const float* __restrict__ bb,
    int* __restrict__ flags) {
  __shared__ u16 smh[64 * 512];          // h staged as [b][512 k^swz]   (64 KB)
  __shared__ float gl[64 * 68];          // gates [64 rows][64+4 b]      (17 KB)

  const int tid = threadIdx.x;
  const int lane = tid & 63;
  const int wid = tid >> 6;
  const int blk = blockIdx.x;
  const int dir = blk >> 5;
  const int j0 = (blk & 31) << 4;

  const float* wih = dir ? wihb : wihf;
  const float* whh = dir ? whhb : whhf;
  const float* bias = dir ? bb : bf;

  const int m = wid >> 1, n = wid & 1;
  const int l31 = lane & 31;
  const int hi = lane >> 5;

  // A-operand (weights) -> registers, once. local row lr = strip*16 + r
  const int lr = m * 32 + l31;
  const int strip = lr >> 4, rr = lr & 15;
  const int grow = strip * 512 + j0 + rr;
  const float* pih = wih + (size_t)grow * 192 + 8 * hi;
  const float* phh = whh + (size_t)grow * 512 + 8 * hi;
  u32x4 aw[44];
#pragma unroll
  for (int kt = 0; kt < 44; ++kt) {
    const float* p = (kt < 12) ? (pih + kt * 16) : (phh + (kt - 12) * 16);
    f32x4v f0 = *(const f32x4v*)p;
    f32x4v f1 = *(const f32x4v*)(p + 4);
    u32x4 a;
    a[0] = packbf(f0[0], f0[1]); a[1] = packbf(f0[2], f0[3]);
    a[2] = packbf(f1[0], f1[1]); a[3] = packbf(f1[2], f1[3]);
    aw[kt] = a;
  }

  u16* hb_dT = hbuf + dir * 65536;       // [2 parity][64 b][512 k]

  const int bb_ = n * 32 + l31;          // batch column for B-frags
  const int swzr = (bb_ & 15) << 4;      // byte swizzle within 1KB row
  const char* hbase = (const char*)smh + bb_ * 1024;
  const int hoff = hi * 16;

  // pointwise mapping: thread -> (batch pb, 4 consecutive j at pj)
  const int pb = tid >> 2;
  const int pj = (tid & 3) * 4;
  float creg[4] = {0.f, 0.f, 0.f, 0.f};
  float bI[4], bF[4], bG[4], bO[4];
#pragma unroll
  for (int q = 0; q < 4; ++q) {
    bI[q] = bias[j0 + pj + q];
    bF[q] = bias[512 + j0 + pj + q];
    bG[q] = bias[1024 + j0 + pj + q];
    bO[q] = bias[1536 + j0 + pj + q];
  }

  int* myflags = flags + dir * 64;       // 32 flags, 8B apart (256 B / dir)

  for (int t = 0; t < TT; ++t) {
    const int par = t & 1;
    const int tx = dir ? (511 - t) : t;

    // ---- x-fragment prefetch (independent of other blocks; hides under poll)
    u32x4 xf[12];
    const u16* xbase = embX + ((size_t)tx * 64 + bb_) * 192 + 8 * hi;
#pragma unroll
    for (int kt = 0; kt < 12; ++kt) xf[kt] = *(const u32x4*)(xbase + kt * 16);

    // ---- wait for h(t-1): gather all 32 producer flags in one vector load
    if (t) {
      int f = ldflag(myflags + (lane & 31) * 2);
      int guard = 0;
      while (__any(f < t)) {
        if (++guard > 300000) break;    // failsafe: wrong answer > hang
        __builtin_amdgcn_s_sleep(1);
        f = ldflag(myflags + (lane & 31) * 2);
      }
    }

    // ---- stage h_T: global [b][k] (L3) -> LDS [b][k^swz], coalesced dwordx4
    {
      const u16* src = hb_dT + par * 32768;
#pragma unroll
      for (int half = 0; half < 2; ++half) {
        u32x4 v[8];
#pragma unroll
        for (int r = 0; r < 8; ++r) {
          int b = (half * 8 + r) * 4 + wid;
          v[r] = ldg_cc(src + b * 512 + lane * 8);
        }
        asm volatile("s_waitcnt vmcnt(0)" ::: "memory");
#pragma unroll
        for (int r = 0; r < 8; ++r) {
          int b = (half * 8 + r) * 4 + wid;
          int kk = (lane * 8) ^ ((b & 15) << 3);
          *(u32x4*)(smh + b * 512 + kk) = v[r];
        }
      }
    }
    __syncthreads();

    // ---- MFMA: acc[64g][64b] tile (m,n), K = 512(h from LDS) + 192(x regs)
    f32x16 acc;
#pragma unroll
    for (int i = 0; i < 16; ++i) acc[i] = 0.f;
    asm volatile("s_nop 7\ns_nop 7");
#pragma unroll
    for (int kt = 0; kt < 32; ++kt) {
      u32x4 bfrag = *(const u32x4*)(hbase + ((kt * 32 + hoff) ^ swzr));
      asm("v_mfma_f32_32x32x16_bf16 %0, %1, %2, %0" : "+v"(acc) : "v"(aw[kt]), "v"(bfrag));
    }
#pragma unroll
    for (int kt = 0; kt < 12; ++kt) {
      asm("v_mfma_f32_32x32x16_bf16 %0, %1, %2, %0" : "+v"(acc) : "v"(aw[32 + kt]), "v"(xf[kt]));
    }
    asm volatile("s_nop 7\ns_nop 7\ns_nop 7");

    // ---- gates -> LDS  (D layout: col=lane&31, row=(r&3)+8*(r>>2)+4*(lane>>5))
    // (gl no longer aliases smh -> no barrier needed before this write)
#pragma unroll
    for (int r = 0; r < 16; ++r) {
      int row = (r & 3) + 8 * (r >> 2) + 4 * hi;
      gl[(m * 32 + row) * 68 + (n * 32 + l31)] = acc[r];
    }
    __syncthreads();

    // ---- pointwise LSTM cell (fp32); h -> global transposed [b][k] via L3
    {
      u16* dstT = hb_dT + (par ^ 1) * 32768;
      u32 hp0 = 0, hp1 = 0;
#pragma unroll
      for (int q = 0; q < 4; ++q) {
        int j = pj + q;
        float gi = gl[j * 68 + pb] + bI[q];
        float gf = gl[(16 + j) * 68 + pb] + bF[q];
        float gg = gl[(32 + j) * 68 + pb] + bG[q];
        float go = gl[(48 + j) * 68 + pb] + bO[q];
        float cn = sigm(gf) * creg[q] + sigm(gi) * tanhx(gg);
        creg[q] = cn;
        float h = sigm(go) * tanhx(cn);
        u32 h16 = (u32)f2b(h);
        if (q == 0) hp0 = h16;
        else if (q == 1) hp0 |= h16 << 16;
        else if (q == 2) hp1 = h16;
        else hp1 |= h16 << 16;
      }
      u32x2 hv; hv[0] = hp0; hv[1] = hp1;
      stg_cc8(dstT + pb * 512 + j0 + pj, hv);
      // hs output [t][b][1024] directly from registers (plain cached store)
      *(u32x2*)(hs + ((size_t)tx * 64 + pb) * 1024 + dir * 512 + j0 + pj) = hv;
    }

    // ---- publish: drain h stores, then one flag store per block
    if (t != TT - 1) {
      asm volatile("s_waitcnt vmcnt(0)" ::: "memory");
      __syncthreads();
      if (tid == 0) stflag(myflags + (blk & 31) * 2, t + 1);
    }
  }
}

// ---- 3. emission: feats[row=t*64+b][c] = hs_row . w_cls[c] + b_cls[c] ----
__global__ __launch_bounds__(256) void k_emis(const u16* __restrict__ hs,
                                              const float* __restrict__ wcls,
                                              const float* __restrict__ bcls,
                                              float* __restrict__ feats) {
  __shared__ float wl[10240];
  int tid = threadIdx.x;
  for (int i = tid; i < 10240; i += 256) wl[i] = wcls[i];
  __syncthreads();
  int row = blockIdx.x * 256 + tid;
  const u16* hrow = hs + (size_t)row * 1024;
  float acc[10];
#pragma unroll
  for (int c = 0; c < 10; ++c) acc[c] = bcls[c];
  for (int k0 = 0; k0 < 1024; k0 += 8) {
    u32x4 v = *(const u32x4*)(hrow + k0);
    float x0 = __uint_as_float(v[0] << 16);
    float x1 = __uint_as_float(v[0] & 0xffff0000u);
    float x2 = __uint_as_float(v[1] << 16);
    float x3 = __uint_as_float(v[1] & 0xffff0000u);
    float x4 = __uint_as_float(v[2] << 16);
    float x5 = __uint_as_float(v[2] & 0xffff0000u);
    float x6 = __uint_as_float(v[3] << 16);
    float x7 = __uint_as_float(v[3] & 0xffff0000u);
#pragma unroll
    for (int c = 0; c < 10; ++c) {
      const float* w = &wl[c * 1024 + k0];
      f32x4v wa = *(const f32x4v*)w;
      f32x4v wb = *(const f32x4v*)(w + 4);
      acc[c] += x0 * wa[0] + x1 * wa[1] + x2 * wa[2] + x3 * wa[3] +
                x4 * wb[0] + x5 * wb[1] + x6 * wb[2] + x7 * wb[3];
    }
  }
#pragma unroll
  for (int c = 0; c < 10; ++c) feats[(size_t)row * 10 + c] = acc[c];
}

// ---- 4. CRF forward + gold score, one wave per batch element ----
__global__ void k_crf(const float* __restrict__ feats, const float* __restrict__ trans,
                      const int* __restrict__ btag, float* __restrict__ res) {
  int b = blockIdx.x;
  int lane = threadIdx.x;
  float tr[10];
  int to = lane < 10 ? lane : 9;
#pragma unroll
  for (int f = 0; f < 10; ++f) tr[f] = trans[to * 10 + f];
  float al[10];
#pragma unroll
  for (int f = 0; f < 10; ++f) al[f] = (f == 8) ? 0.f : -10000.f;  // START_ID=8
  float fe_next = (lane < 10) ? feats[(size_t)b * 10 + lane] : 0.f;
  for (int t = 0; t < 512; ++t) {
    float fe = fe_next;
    if (t < 511)
      fe_next = (lane < 10) ? feats[((size_t)(t + 1) * 64 + b) * 10 + lane] : 0.f;
    float mx = -3.0e38f;
#pragma unroll
    for (int f = 0; f < 10; ++f) mx = fmaxf(mx, al[f] + tr[f]);
    float s = 0.f;
#pragma unroll
    for (int f = 0; f < 10; ++f) s += __expf(al[f] + tr[f] - mx);
    float an = mx + __logf(s) + fe;
#pragma unroll
    for (int f = 0; f < 10; ++f) al[f] = __shfl(an, f);
  }
  float mx = -3.0e38f;
#pragma unroll
  for (int f = 0; f < 10; ++f) mx = fmaxf(mx, al[f]);
  float s = 0.f;
#pragma unroll
  for (int f = 0; f < 10; ++f) s += __expf(al[f] - mx);
  float fwd = mx + __logf(s);
  // gold score
  float g = 0.f;
  for (int t = lane; t < 512; t += 64) {
    int tg = btag[b * 512 + t];
    int pv = (t == 0) ? 8 : btag[b * 512 + t - 1];
    g += trans[tg * 10 + pv] + feats[((size_t)t * 64 + b) * 10 + tg];
  }
#pragma unroll
  for (int off = 32; off > 0; off >>= 1) g += __shfl_down(g, off);
  if (lane == 0) res[b] = fwd - g;
}

// ---- 5. final reduce ----
__global__ void k_fin(const float* __restrict__ res, float* __restrict__ out) {
  float v = res[threadIdx.x];
#pragma unroll
  for (int off = 32; off > 0; off >>= 1) v += __shfl_down(v, off);
  if (threadIdx.x == 0) out[0] = v * (1.f / 64.f);
}

extern "C" void kernel_launch(void* const* d_in, const int* in_sizes, int n_in,
                              void* d_out, int out_size, void* d_ws, size_t ws_size,
                              hipStream_t stream) {
  (void)in_sizes; (void)n_in; (void)out_size;
  if (ws_size < WS_NEED) return;  // visible failure instead of OOB

  const int* bdata = (const int*)d_in[0];
  const int* brad  = (const int*)d_in[1];
  const int* btag  = (const int*)d_in[2];
  const float* cemb = (const float*)d_in[3];
  const float* remb = (const float*)d_in[4];
  const float* wihf = (const float*)d_in[5];
  const float* whhf = (const float*)d_in[6];
  const float* bf   = (const float*)d_in[7];
  const float* wihb = (const float*)d_in[8];
  const float* whhb = (const float*)d_in[9];
  const float* bb   = (const float*)d_in[10];
  const float* wcls = (const float*)d_in[11];
  const float* bcls = (const float*)d_in[12];
  const float* trans = (const float*)d_in[13];

  char* ws = (char*)d_ws;
  u16* embX = (u16*)(ws + OFF_EMBX);
  u16* hs   = (u16*)(ws + OFF_HS);
  u16* hbuf = (u16*)(ws + OFF_HBUF);
  int* flags = (int*)(ws + OFF_BAR);
  float* feats = (float*)(ws + OFF_FEAT);
  float* res = (float*)(ws + OFF_RES);

  // zero h0 (both dirs, both parities) + ready-flags, every launch
  hipMemsetAsync(ws + OFF_HBUF, 0, 262144 + 512, stream);

  k_embed<<<512, 256, 0, stream>>>(bdata, brad, cemb, remb, embX);
  k_lstm<<<64, 256, 0, stream>>>(embX, hbuf, hs, wihf, whhf, bf, wihb, whhb, bb, flags);
  k_emis<<<128, 256, 0, stream>>>(hs, wcls, bcls, feats);
  k_crf<<<64, 64, 0, stream>>>(feats, trans, btag, res);
  k_fin<<<1, 64, 0, stream>>>(res, (float*)d_out);
}

// Round 5
// 2817.858 us; speedup vs baseline: 5.5203x; 1.1419x over previous
//
#include <hip/hip_runtime.h>

typedef unsigned short u16;
typedef unsigned int u32;
typedef float f32x16 __attribute__((ext_vector_type(16)));
typedef float f32x4v __attribute__((ext_vector_type(4)));
typedef unsigned int u32x4 __attribute__((ext_vector_type(4)));
typedef unsigned int u32x2 __attribute__((ext_vector_type(2)));

#define TT 512
#define NBLK 64

// ---- ws layout (bytes) ----
static const size_t OFF_EMBX = 0;          // u16 [512][64][192]  = 12,582,912
static const size_t OFF_HS   = 12582912;   // u16 [512][64][1024] = 67,108,864
static const size_t OFF_HBUF = 79691776;   // u16 [dir][par][64 b][512 k] = 262,144
static const size_t OFF_BAR  = 79953920;   // int flags[2][64] (512 B, zeroed each launch)
static const size_t OFF_FEAT = 79954176;   // f32 [512*64][10]    = 1,310,720
static const size_t OFF_RES  = 81264896;   // f32 [64]
static const size_t WS_NEED  = 81265152;

__device__ inline u32 packbf(float a, float b) {
  u32 ua = __float_as_uint(a); ua += 0x7fffu + ((ua >> 16) & 1u);
  u32 ub = __float_as_uint(b); ub += 0x7fffu + ((ub >> 16) & 1u);
  return (ua >> 16) | (ub & 0xffff0000u);
}
__device__ inline u16 f2b(float a) {
  u32 u = __float_as_uint(a); u += 0x7fffu + ((u >> 16) & 1u);
  return (u16)(u >> 16);
}
__device__ inline float sigm(float x) { return 1.f / (1.f + __expf(-x)); }
__device__ inline float tanhx(float x) {
  float e = __expf(-2.f * fabsf(x));
  float t = (1.f - e) / (1.f + e);
  return (x < 0.f) ? -t : t;
}

// L3-coherent (L1/L2-bypassing) access helpers — cross-XCD exchange w/o fences
__device__ inline u32x4 ldg_cc(const u16* p) {
  u32x4 r;
  asm volatile("global_load_dwordx4 %0, %1, off sc0 sc1"
               : "=v"(r) : "v"(p) : "memory");
  return r;
}
__device__ inline void stg_cc8(u16* p, u32x2 v) {
  asm volatile("global_store_dwordx2 %0, %1, off sc0 sc1"
               :: "v"(p), "v"(v) : "memory");
}
__device__ inline int ldflag(const int* p) {
  int r;
  asm volatile("global_load_dword %0, %1, off sc0 sc1"
               : "=v"(r) : "v"(p) : "memory");
  asm volatile("s_waitcnt vmcnt(0)" ::: "memory");
  return r;
}
__device__ inline void stflag(int* p, int v) {
  asm volatile("global_store_dword %0, %1, off sc0 sc1"
               :: "v"(p), "v"(v) : "memory");
}

// ---- 1. embedding gather: embX[t][b][0..191] bf16 ----
__global__ __launch_bounds__(256) void k_embed(const int* __restrict__ bdata,
                                               const int* __restrict__ brad,
                                               const float* __restrict__ cemb,
                                               const float* __restrict__ remb,
                                               u16* __restrict__ embX) {
  int t = blockIdx.x;
  int tid = threadIdx.x;
#pragma unroll
  for (int r = 0; r < 6; ++r) {
    int cc = r * 256 + tid;           // 0..1535 = 64 b * 24 chunks
    int b = cc / 24;
    int j = cc - b * 24;              // chunk of 8 floats
    int ic = bdata[b * TT + t];
    int ir = brad[b * TT + t];
    const float* src = (j < 16) ? (cemb + (size_t)ic * 128 + j * 8)
                                : (remb + (size_t)ir * 64 + (j - 16) * 8);
    f32x4v f0 = *(const f32x4v*)src;
    f32x4v f1 = *(const f32x4v*)(src + 4);
    u32x4 o;
    o[0] = packbf(f0[0], f0[1]); o[1] = packbf(f0[2], f0[3]);
    o[2] = packbf(f1[0], f1[1]); o[3] = packbf(f1[2], f1[3]);
    *(u32x4*)(embX + ((size_t)t * 64 + b) * 192 + j * 8) = o;
  }
}

// ---- 2. persistent bidirectional LSTM ----
// 64 blocks: blk>>5 = dir, (blk&31)*16 = hidden slice j0. 256 thr = 4 waves.
// h exchanged transposed [b][k] through L3 (sc0 sc1); per-producer flags.
// A-row map gate*512+j0+(l31&7)+8m => thread's acc = i,f,g,o x 4 consecutive j
// for ONE batch column -> pointwise entirely in registers (no gate LDS pass).
__global__ __launch_bounds__(256, 1) void k_lstm(
    const u16* __restrict__ embX, u16* __restrict__ hbuf, u16* __restrict__ hs,
    const float* __restrict__ wihf, const float* __restrict__ whhf, const float* __restrict__ bf,
    const float* __restrict__ wihb, const float* __restrict__ whhb, const float* __restrict__ bb,
    int* __restrict__ flags) {
  __shared__ u16 smh[64 * 512];          // h staged as [b][512 k^swz]   (64 KB)

  const int tid = threadIdx.x;
  const int lane = tid & 63;
  const int wid = tid >> 6;
  const int blk = blockIdx.x;
  const int dir = blk >> 5;
  const int j0 = (blk & 31) << 4;

  const float* wih = dir ? wihb : wihf;
  const float* whh = dir ? whhb : whhf;
  const float* bias = dir ? bb : bf;

  const int m = wid >> 1, n = wid & 1;
  const int l31 = lane & 31;
  const int hi = lane >> 5;

  // A-operand (weights) -> registers, once.
  // local A-row lr = m*32 + l31; gate = l31>>3; jloc = (l31&7) + 8*m
  const int gate = l31 >> 3;
  const int jloc = (l31 & 7) + 8 * m;
  const int grow = gate * 512 + j0 + jloc;
  const float* pih = wih + (size_t)grow * 192 + 8 * hi;
  const float* phh = whh + (size_t)grow * 512 + 8 * hi;
  u32x4 aw[44];
#pragma unroll
  for (int kt = 0; kt < 44; ++kt) {
    const float* p = (kt < 12) ? (pih + kt * 16) : (phh + (kt - 12) * 16);
    f32x4v f0 = *(const f32x4v*)p;
    f32x4v f1 = *(const f32x4v*)(p + 4);
    u32x4 a;
    a[0] = packbf(f0[0], f0[1]); a[1] = packbf(f0[2], f0[3]);
    a[2] = packbf(f1[0], f1[1]); a[3] = packbf(f1[2], f1[3]);
    aw[kt] = a;
  }

  u16* hb_dT = hbuf + dir * 65536;       // [2 parity][64 b][512 k]

  const int bb_ = n * 32 + l31;          // batch column for B-frags
  const int swzr = (bb_ & 15) << 4;      // byte swizzle within 1KB row
  const char* hbase = (const char*)smh + bb_ * 1024;
  const int hoff = hi * 16;

  // pointwise: this thread owns (b = bb_, j = j0 + 8m + 4hi + q), q=0..3
  const int jme = j0 + 8 * m + 4 * hi;
  float creg[4] = {0.f, 0.f, 0.f, 0.f};
  float bI[4], bF[4], bG[4], bO[4];
#pragma unroll
  for (int q = 0; q < 4; ++q) {
    bI[q] = bias[jme + q];
    bF[q] = bias[512 + jme + q];
    bG[q] = bias[1024 + jme + q];
    bO[q] = bias[1536 + jme + q];
  }

  int* myflags = flags + dir * 64;       // 32 flags, 8B apart (256 B / dir)

  for (int t = 0; t < TT; ++t) {
    const int par = t & 1;
    const int tx = dir ? (511 - t) : t;

    // ---- x-fragment prefetch (independent of other blocks; hides under poll)
    u32x4 xf[12];
    const u16* xbase = embX + ((size_t)tx * 64 + bb_) * 192 + 8 * hi;
#pragma unroll
    for (int kt = 0; kt < 12; ++kt) xf[kt] = *(const u32x4*)(xbase + kt * 16);

    // ---- wait for h(t-1): gather all 32 producer flags in one vector load
    if (t) {
      int f = ldflag(myflags + (lane & 31) * 2);
      int guard = 0;
      while (__any(f < t)) {
        if (++guard > 20000) break;     // failsafe: wrong answer > hang
        f = ldflag(myflags + (lane & 31) * 2);
      }
    }

    // ---- stage h_T: 16 loads -> ONE vmcnt(0) -> 16 LDS writes (single RT)
    {
      const u16* src = hb_dT + par * 32768;
      u32x4 v[16];
#pragma unroll
      for (int r = 0; r < 16; ++r) {
        int b = r * 4 + wid;
        v[r] = ldg_cc(src + b * 512 + lane * 8);
      }
      asm volatile("s_waitcnt vmcnt(0)" ::: "memory");
#pragma unroll
      for (int r = 0; r < 16; ++r) {
        int b = r * 4 + wid;
        int kk = (lane * 8) ^ ((b & 15) << 3);
        *(u32x4*)(smh + b * 512 + kk) = v[r];
      }
    }
    __syncthreads();

    // ---- MFMA: acc rows = gates (i,f,g,o x j), cols = batch; K=512(h)+192(x)
    f32x16 acc;
#pragma unroll
    for (int i = 0; i < 16; ++i) acc[i] = 0.f;
    asm volatile("s_nop 7\ns_nop 7");
#pragma unroll
    for (int kt = 0; kt < 32; ++kt) {
      u32x4 bfrag = *(const u32x4*)(hbase + ((kt * 32 + hoff) ^ swzr));
      asm("v_mfma_f32_32x32x16_bf16 %0, %1, %2, %0" : "+v"(acc) : "v"(aw[kt]), "v"(bfrag));
    }
#pragma unroll
    for (int kt = 0; kt < 12; ++kt) {
      asm("v_mfma_f32_32x32x16_bf16 %0, %1, %2, %0" : "+v"(acc) : "v"(aw[32 + kt]), "v"(xf[kt]));
    }
    asm volatile("s_nop 7\ns_nop 7\ns_nop 7");

    // ---- pointwise LSTM cell directly on accumulators (no LDS round trip)
    // acc[q]=i, acc[4+q]=f, acc[8+q]=g, acc[12+q]=o for j=jme+q, b=bb_
    {
      u16* dstT = hb_dT + (par ^ 1) * 32768;
      u32 hp0 = 0, hp1 = 0;
#pragma unroll
      for (int q = 0; q < 4; ++q) {
        float gi = acc[q] + bI[q];
        float gf = acc[4 + q] + bF[q];
        float gg = acc[8 + q] + bG[q];
        float go = acc[12 + q] + bO[q];
        float cn = sigm(gf) * creg[q] + sigm(gi) * tanhx(gg);
        creg[q] = cn;
        float h = sigm(go) * tanhx(cn);
        u32 h16 = (u32)f2b(h);
        if (q == 0) hp0 = h16;
        else if (q == 1) hp0 |= h16 << 16;
        else if (q == 2) hp1 = h16;
        else hp1 |= h16 << 16;
      }
      u32x2 hv; hv[0] = hp0; hv[1] = hp1;
      stg_cc8(dstT + bb_ * 512 + jme, hv);
      // hs output [t][b][1024] directly from registers (plain cached store)
      *(u32x2*)(hs + ((size_t)tx * 64 + bb_) * 1024 + dir * 512 + jme) = hv;
    }

    // ---- publish: drain stores, block barrier, one flag store
    if (t != TT - 1) {
      asm volatile("s_waitcnt vmcnt(0)" ::: "memory");
      __syncthreads();
      if (tid == 0) stflag(myflags + (blk & 31) * 2, t + 1);
    }
  }
}

// ---- 3. emission: feats[row=t*64+b][c] = hs_row . w_cls[c] + b_cls[c] ----
__global__ __launch_bounds__(256) void k_emis(const u16* __restrict__ hs,
                                              const float* __restrict__ wcls,
                                              const float* __restrict__ bcls,
                                              float* __restrict__ feats) {
  __shared__ float wl[10240];
  int tid = threadIdx.x;
  for (int i = tid; i < 10240; i += 256) wl[i] = wcls[i];
  __syncthreads();
  int row = blockIdx.x * 256 + tid;
  const u16* hrow = hs + (size_t)row * 1024;
  float acc[10];
#pragma unroll
  for (int c = 0; c < 10; ++c) acc[c] = bcls[c];
  for (int k0 = 0; k0 < 1024; k0 += 8) {
    u32x4 v = *(const u32x4*)(hrow + k0);
    float x0 = __uint_as_float(v[0] << 16);
    float x1 = __uint_as_float(v[0] & 0xffff0000u);
    float x2 = __uint_as_float(v[1] << 16);
    float x3 = __uint_as_float(v[1] & 0xffff0000u);
    float x4 = __uint_as_float(v[2] << 16);
    float x5 = __uint_as_float(v[2] & 0xffff0000u);
    float x6 = __uint_as_float(v[3] << 16);
    float x7 = __uint_as_float(v[3] & 0xffff0000u);
#pragma unroll
    for (int c = 0; c < 10; ++c) {
      const float* w = &wl[c * 1024 + k0];
      f32x4v wa = *(const f32x4v*)w;
      f32x4v wb = *(const f32x4v*)(w + 4);
      acc[c] += x0 * wa[0] + x1 * wa[1] + x2 * wa[2] + x3 * wa[3] +
                x4 * wb[0] + x5 * wb[1] + x6 * wb[2] + x7 * wb[3];
    }
  }
#pragma unroll
  for (int c = 0; c < 10; ++c) feats[(size_t)row * 10 + c] = acc[c];
}

// ---- 4. CRF forward + gold score, one wave per batch element ----
__global__ void k_crf(const float* __restrict__ feats, const float* __restrict__ trans,
                      const int* __restrict__ btag, float* __restrict__ res) {
  int b = blockIdx.x;
  int lane = threadIdx.x;
  float tr[10];
  int to = lane < 10 ? lane : 9;
#pragma unroll
  for (int f = 0; f < 10; ++f) tr[f] = trans[to * 10 + f];
  float al[10];
#pragma unroll
  for (int f = 0; f < 10; ++f) al[f] = (f == 8) ? 0.f : -10000.f;  // START_ID=8
  float fe_next = (lane < 10) ? feats[(size_t)b * 10 + lane] : 0.f;
  for (int t = 0; t < 512; ++t) {
    float fe = fe_next;
    if (t < 511)
      fe_next = (lane < 10) ? feats[((size_t)(t + 1) * 64 + b) * 10 + lane] : 0.f;
    float mx = -3.0e38f;
#pragma unroll
    for (int f = 0; f < 10; ++f) mx = fmaxf(mx, al[f] + tr[f]);
    float s = 0.f;
#pragma unroll
    for (int f = 0; f < 10; ++f) s += __expf(al[f] + tr[f] - mx);
    float an = mx + __logf(s) + fe;
#pragma unroll
    for (int f = 0; f < 10; ++f) al[f] = __shfl(an, f);
  }
  float mx = -3.0e38f;
#pragma unroll
  for (int f = 0; f < 10; ++f) mx = fmaxf(mx, al[f]);
  float s = 0.f;
#pragma unroll
  for (int f = 0; f < 10; ++f) s += __expf(al[f] - mx);
  float fwd = mx + __logf(s);
  // gold score
  float g = 0.f;
  for (int t = lane; t < 512; t += 64) {
    int tg = btag[b * 512 + t];
    int pv = (t == 0) ? 8 : btag[b * 512 + t - 1];
    g += trans[tg * 10 + pv] + feats[((size_t)t * 64 + b) * 10 + tg];
  }
#pragma unroll
  for (int off = 32; off > 0; off >>= 1) g += __shfl_down(g, off);
  if (lane == 0) res[b] = fwd - g;
}

// ---- 5. final reduce ----
__global__ void k_fin(const float* __restrict__ res, float* __restrict__ out) {
  float v = res[threadIdx.x];
#pragma unroll
  for (int off = 32; off > 0; off >>= 1) v += __shfl_down(v, off);
  if (threadIdx.x == 0) out[0] = v * (1.f / 64.f);
}

extern "C" void kernel_launch(void* const* d_in, const int* in_sizes, int n_in,
                              void* d_out, int out_size, void* d_ws, size_t ws_size,
                              hipStream_t stream) {
  (void)in_sizes; (void)n_in; (void)out_size;
  if (ws_size < WS_NEED) return;  // visible failure instead of OOB

  const int* bdata = (const int*)d_in[0];
  const int* brad  = (const int*)d_in[1];
  const int* btag  = (const int*)d_in[2];
  const float* cemb = (const float*)d_in[3];
  const float* remb = (const float*)d_in[4];
  const float* wihf = (const float*)d_in[5];
  const float* whhf = (const float*)d_in[6];
  const float* bf   = (const float*)d_in[7];
  const float* wihb = (const float*)d_in[8];
  const float* whhb = (const float*)d_in[9];
  const float* bb   = (const float*)d_in[10];
  const float* wcls = (const float*)d_in[11];
  const float* bcls = (const float*)d_in[12];
  const float* trans = (const float*)d_in[13];

  char* ws = (char*)d_ws;
  u16* embX = (u16*)(ws + OFF_EMBX);
  u16* hs   = (u16*)(ws + OFF_HS);
  u16* hbuf = (u16*)(ws + OFF_HBUF);
  int* flags = (int*)(ws + OFF_BAR);
  float* feats = (float*)(ws + OFF_FEAT);
  float* res = (float*)(ws + OFF_RES);

  // zero h0 (both dirs, both parities) + ready-flags, every launch
  hipMemsetAsync(ws + OFF_HBUF, 0, 262144 + 512, stream);

  k_embed<<<512, 256, 0, stream>>>(bdata, brad, cemb, remb, embX);
  k_lstm<<<64, 256, 0, stream>>>(embX, hbuf, hs, wihf, whhf, bf, wihb, whhb, bb, flags);
  k_emis<<<128, 256, 0, stream>>>(hs, wcls, bcls, feats);
  k_crf<<<64, 64, 0, stream>>>(feats, trans, btag, res);
  k_fin<<<1, 64, 0, stream>>>(res, (float*)d_out);
}